// Round 5
// baseline (367.051 us; speedup 1.0000x reference)
//
#include <hip/hip_runtime.h>

typedef unsigned short u16;
typedef unsigned int u32;
typedef __bf16 bf16_t;
typedef __attribute__((ext_vector_type(8))) bf16_t bf16x8;
typedef __attribute__((ext_vector_type(4))) float f32x4;
typedef __attribute__((ext_vector_type(16))) float f32x16;
typedef __attribute__((ext_vector_type(2))) unsigned int u32x2;

__device__ inline u16 f2bf(float f) {
    union { float f; u32 u; } v; v.f = f;
    u32 u = v.u;
    u32 r = (u + 0x7fffu + ((u >> 16) & 1u)) >> 16;
    return (u16)r;
}

__device__ inline u32 cvt_pk_bf16(float lo, float hi) {
    u32 r;
    asm("v_cvt_pk_bf16_f32 %0, %1, %2" : "=v"(r) : "v"(lo), "v"(hi));
    return r;
}

// async global->LDS, 16B per lane; LDS dest is wave-uniform base + lane*16
__device__ inline void async_cp16(const void* g, void* l) {
    __builtin_amdgcn_global_load_lds((const __attribute__((address_space(1))) void*)g,
                                     (__attribute__((address_space(3))) void*)l, 16, 0, 0);
}

// ---------------- fp32 -> bf16 convert, 3 arrays fused ----------------
__global__ __launch_bounds__(256) void cvt3(const float* __restrict__ a,
                                            const float* __restrict__ b,
                                            const float* __restrict__ c,
                                            u16* __restrict__ oa, u16* __restrict__ ob,
                                            u16* __restrict__ oc) {
    int z = blockIdx.y;
    const float* in = z == 0 ? a : (z == 1 ? b : c);
    u16* out = z == 0 ? oa : (z == 1 ? ob : oc);
    int i = (blockIdx.x * 256 + threadIdx.x) * 4;
    float4 f = *(const float4*)(in + i);
    ushort4 o;
    o.x = f2bf(f.x); o.y = f2bf(f.y); o.z = f2bf(f.z); o.w = f2bf(f.w);
    *(ushort4*)(out + i) = o;
}

// ---------------- W[K][N] fp32 -> WT[N][K] bf16, 2 matrices fused ----------------
__global__ __launch_bounds__(256) void transpose2(const float* __restrict__ W0,
                                                  u16* __restrict__ T0,
                                                  const float* __restrict__ W1,
                                                  u16* __restrict__ T1,
                                                  int K, int N) {
    const float* W = blockIdx.z == 0 ? W0 : W1;
    u16* WT = blockIdx.z == 0 ? T0 : T1;
    __shared__ float tile[32][33];
    int tr0 = blockIdx.x * 32;
    int tc0 = blockIdx.y * 32;
    int t = threadIdx.x;
    for (int i = 0; i < 4; i++) {
        int idx = t + i * 256; int r = idx >> 5, c = idx & 31;
        tile[r][c] = W[(size_t)(tr0 + r) * N + tc0 + c];
    }
    __syncthreads();
    for (int i = 0; i < 4; i++) {
        int idx = t + i * 256; int r = idx >> 5, c = idx & 31;
        WT[(size_t)(tc0 + r) * K + tr0 + c] = f2bf(tile[c][r]);
    }
}

// ---------------- big-GEMM v3: BM=256 BN=128 BK=64, triple-buffer, counted vmcnt ----------------
template <typename OUT_T>
__global__ __launch_bounds__(512, 2) void gemm_bt2(const u16* __restrict__ A,
                                                   const u16* __restrict__ BT,
                                                   const float* __restrict__ bias,
                                                   OUT_T* __restrict__ C,
                                                   int M, int N, int K, int ldout) {
    __shared__ u16 smem[3 * 24576];
    int t = threadIdx.x, lane = t & 63, wv = t >> 6;
    int quad = lane >> 4, c16 = lane & 15;
    int rx = c16 & 7;
    int wr = wv >> 1, wc = wv & 1;      // wave tile origin (wr*64, wc*64)

    // 2D per-XCD chunk: XCD = bid&7 (HW round-robin), 32 blocks/XCD
    int bid = blockIdx.x;
    int xcd = bid & 7;
    int loc = bid >> 3;                  // 0..31
    int bm = (((xcd >> 1) << 2) + (loc & 3)) << 8;   // 4 m-tiles per XCD region
    int bn = (((xcd & 1) << 3) + (loc >> 2)) << 7;   // 8 n-tiles per XCD region

    f32x4 acc[4][4] = {};

    int srow = wv * 8 + (lane >> 3);
    int scol = ((lane & 7) ^ (lane >> 3)) * 8;
    const u16* Ag = A + (size_t)(bm + srow) * K + scol;
    const u16* Bg = BT + (size_t)(bn + srow) * K + scol;

    auto STAGE = [&](int kt, int d) {
        u16* base = smem + d * 24576;
        u16* ad = base + (size_t)(wv * 8) * 64;
        u16* bd = base + 16384 + (size_t)(wv * 8) * 64;
        const u16* ag = Ag + (size_t)kt * 64;
        const u16* bg = Bg + (size_t)kt * 64;
        for (int p = 0; p < 4; p++)
            async_cp16(ag + (size_t)(p * 64) * K, ad + p * 4096);
        for (int p = 0; p < 2; p++)
            async_cp16(bg + (size_t)(p * 64) * K, bd + p * 4096);
    };

    const int NT = K >> 6;
    STAGE(0, 0);
    STAGE(1, 1);

    for (int tt = 0; tt < NT; tt++) {
        if (tt + 1 < NT) asm volatile("s_waitcnt vmcnt(6)" ::: "memory");
        else             asm volatile("s_waitcnt vmcnt(0)" ::: "memory");
        __builtin_amdgcn_s_barrier();
        if (tt + 2 < NT) STAGE(tt + 2, (tt + 2) % 3);

        const u16* sA = smem + (tt % 3) * 24576;
        const u16* sB = sA + 16384;

        for (int rh = 0; rh < 2; rh++) {
            bf16x8 af[2][2];
            for (int mi = 0; mi < 2; mi++)
                for (int kk = 0; kk < 2; kk++)
                    af[mi][kk] = *(const bf16x8*)&sA[(wr * 64 + rh * 32 + mi * 16 + c16) * 64 +
                                                     (((kk * 4 + quad) ^ rx) * 8)];
            for (int ch = 0; ch < 2; ch++) {
                bf16x8 bf[2][2];
                for (int ni = 0; ni < 2; ni++)
                    for (int kk = 0; kk < 2; kk++)
                        bf[ni][kk] = *(const bf16x8*)&sB[(wc * 64 + ch * 32 + ni * 16 + c16) * 64 +
                                                         (((kk * 4 + quad) ^ rx) * 8)];
                __builtin_amdgcn_s_setprio(1);
                for (int kk = 0; kk < 2; kk++)
                    for (int mi = 0; mi < 2; mi++)
                        for (int ni = 0; ni < 2; ni++)
                            acc[rh * 2 + mi][ch * 2 + ni] = __builtin_amdgcn_mfma_f32_16x16x32_bf16(
                                af[mi][kk], bf[ni][kk], acc[rh * 2 + mi][ch * 2 + ni], 0, 0, 0);
                __builtin_amdgcn_s_setprio(0);
            }
        }
    }

    for (int mi = 0; mi < 4; mi++) {
        for (int ni = 0; ni < 4; ni++) {
            int col = bn + wc * 64 + ni * 16 + c16;
            float bv = bias[col];
            for (int p = 0; p < 4; p++) {
                int row = bm + wr * 64 + mi * 16 + quad * 4 + p;
                float v = acc[mi][ni][p] + bv;
                size_t off = (size_t)row * ldout + col;
                if constexpr (__is_same(OUT_T, u16)) C[off] = f2bf(v);
                else C[off] = v;
            }
        }
    }
}

// ---------------- K/V projection, split-K with fp32 atomic partials ----------------
__global__ __launch_bounds__(256) void gemm_kv_sk(const u16* __restrict__ kbf,
                                                  const u16* __restrict__ vbf,
                                                  const u16* __restrict__ WkT,
                                                  const u16* __restrict__ WvT,
                                                  float* __restrict__ kacc,
                                                  float* __restrict__ vacc,
                                                  int K, int KS) {
    bool isv = blockIdx.y == 1;
    const u16* A = isv ? vbf : kbf;
    const u16* BT = isv ? WvT : WkT;
    float* aco = isv ? vacc : kacc;
    __shared__ u16 sA[128 * 32];
    __shared__ u16 sB[128 * 32];
    int t = threadIdx.x, lane = t & 63, wv = t >> 6;
    int quad = lane >> 4, c16 = lane & 15;
    int bm = blockIdx.x * 128;
    int wm = (wv & 1) * 64, wn = (wv >> 1) * 64;
    f32x4 acc[4][4] = {};

    int srow = wv * 32 + (lane >> 2);
    int scol = (lane & 3) * 8;
    const u16* Ag = A + (size_t)(bm + srow) * K + scol;
    const u16* Bg = BT + (size_t)srow * K + scol;
    u16* sAd = &sA[(wv * 32) * 32];
    u16* sBd = &sB[(wv * 32) * 32];

    int kbeg = blockIdx.z * KS;
    for (int k0 = kbeg; k0 < kbeg + KS; k0 += 32) {
        __syncthreads();
        async_cp16(Ag + k0, sAd);
        async_cp16(Ag + (size_t)16 * K + k0, sAd + 16 * 32);
        async_cp16(Bg + k0, sBd);
        async_cp16(Bg + (size_t)16 * K + k0, sBd + 16 * 32);
        __syncthreads();
        bf16x8 af[4], bfr[4];
        for (int mi = 0; mi < 4; mi++)
            af[mi] = *(const bf16x8*)&sA[(wm + mi * 16 + c16) * 32 + quad * 8];
        for (int ni = 0; ni < 4; ni++)
            bfr[ni] = *(const bf16x8*)&sB[(wn + ni * 16 + c16) * 32 + quad * 8];
        for (int mi = 0; mi < 4; mi++)
            for (int ni = 0; ni < 4; ni++)
                acc[mi][ni] = __builtin_amdgcn_mfma_f32_16x16x32_bf16(
                    af[mi], bfr[ni], acc[mi][ni], 0, 0, 0);
    }

    for (int mi = 0; mi < 4; mi++)
        for (int ni = 0; ni < 4; ni++) {
            int col = wn + ni * 16 + c16;
            for (int p = 0; p < 4; p++) {
                int row = bm + wm + mi * 16 + quad * 4 + p;
                atomicAdd(&aco[(size_t)row * 128 + col], acc[mi][ni][p]);
            }
        }
}

// ---------------- kv epilogue: +bias, ->bf16; z=0: khb copy; z=1: vhT transpose ----------------
__global__ __launch_bounds__(256) void cvt_kv(const float* __restrict__ kacc,
                                              const float* __restrict__ vacc,
                                              const float* __restrict__ bk,
                                              const float* __restrict__ bv,
                                              u16* __restrict__ khb,
                                              u16* __restrict__ vhT,
                                              int M) {
    int t = threadIdx.x;
    int tr0 = blockIdx.x * 32;
    int tc0 = blockIdx.y * 32;
    if (blockIdx.z == 0) {
        for (int i = 0; i < 4; i++) {
            int idx = t + i * 256; int r = idx >> 5, c = idx & 31;
            khb[(size_t)(tr0 + r) * 128 + tc0 + c] =
                f2bf(kacc[(size_t)(tr0 + r) * 128 + tc0 + c] + bk[tc0 + c]);
        }
    } else {
        __shared__ float tile[32][33];
        for (int i = 0; i < 4; i++) {
            int idx = t + i * 256; int r = idx >> 5, c = idx & 31;
            tile[r][c] = vacc[(size_t)(tr0 + r) * 128 + tc0 + c] + bv[tc0 + c];
        }
        __syncthreads();
        for (int i = 0; i < 4; i++) {
            int idx = t + i * 256; int r = idx >> 5, c = idx & 31;
            vhT[(size_t)(tc0 + r) * M + tr0 + c] = f2bf(tile[c][r]);
        }
    }
}

// ---------------- flash attention v9: 64q x 32kv waves (kv-split), P in regs ----------------
// 4 waves = 2 q-halves x 2 kv-halves over a 128q x 64kv tile. Per wave per
// tile: 8 K-reads (kv-half, SHARED across both 32-q score groups by
// interleaving the two accS chains) + 8 V-reads (shared across q-groups in
// PV) = 16 b128, vs v8's 32 -- same 32 MFMA. T12 keeps P in regs
// (cvt_pk + permlane32_swap per q-group). Register budget: accO 2x4xf32x16
// (AGPR) + qg0's Q held in regs; qg1's Q re-read from global each tile
// (block Q-tile = 32 KB = L1-resident, shared by 4 waves) -> L1 port carries
// Q while LDS carries K/V. kv-half partials combined once at kernel end via
// LDS (pure add: static softmax). lsum = direct fp32 sum of e (RNE-unbiased
// vs rounded P; rel err ~1e-5).
__global__ __launch_bounds__(256, 2) void mqa_attn(const u16* __restrict__ qh,   // [B*S][2048]
                                                   const u16* __restrict__ kh,   // [B*S][128]
                                                   const u16* __restrict__ vhT,  // [128][B*S]
                                                   u16* __restrict__ outp,      // [B*S][2048]
                                                   int S) {
    constexpr float CEXP = 0.08838834764831845f * 1.4426950408889634f;  // scale * log2(e)
    __shared__ u16 smem[33024];           // 66048 B -> 2 blocks/CU (132 KB < 160)
    u16* sK0 = smem;                      // 2 bufs x 8192 u16 ([64][128])
    u16* sV0 = smem + 16384;              // 2 bufs x 8192 u16 ([128][64])

    int t = threadIdx.x, lane = t & 63, wv = t >> 6;
    int l31 = lane & 31, hh = lane >> 5;
    int lx = l31 & 7;                     // row-XOR for swizzled frag reads
    int qs = wv >> 1, kvh = wv & 1;
    int b = blockIdx.z, hb = blockIdx.y;
    int q0w = blockIdx.x * 128 + qs * 64;
    int BS = b * S;

    // qg0 Q frags held in regs: lane holds Q[q0w + l31][st*16 + hh*8 + j]
    bf16x8 aq0[8];
    const u16* qp1;
    {
        const u16* qp0 = qh + (size_t)(BS + q0w + l31) * 2048 + hb * 128 + hh * 8;
#pragma unroll
        for (int st = 0; st < 8; st++) aq0[st] = *(const bf16x8*)(qp0 + st * 16);
        qp1 = qh + (size_t)(BS + q0w + 32 + l31) * 2048 + hb * 128 + hh * 8;
    }

    f32x16 accO0[4] = {};   // qg0: O[q=(r&3)+8(r>>2)+4hh][d=db*32+l31]
    f32x16 accO1[4] = {};   // qg1
    float lsum0 = 0.f, lsum1 = 0.f;

    // ---- staging geometry (pre-swizzled global source, linear LDS dest) ----
    int ksub = lane >> 4, kch = lane & 15;
    int klx = (wv * 4 + ksub) & 7;
    const u16* kgb = kh + (size_t)(BS + wv * 4 + ksub) * 128 + ((kch ^ klx) * 8);
    int vsub = lane >> 3, vch = lane & 7;
    int vlx = vsub & 7;
    const u16* vgb = vhT + (size_t)(wv * 8 + vsub) * 4096 + BS + ((vch ^ vlx) * 8);

    u16* kb0 = sK0 + (wv * 4) * 128;      // + buf*8192 + p*2048
    u16* vb0 = sV0 + (wv * 8) * 64;       // + buf*8192 + p*2048

    auto STAGE = [&](int kv0, int d) {
        u16* kb = kb0 + d * 8192;
        u16* vb = vb0 + d * 8192;
        for (int p = 0; p < 4; p++)
            async_cp16(kgb + (size_t)(kv0 + p * 16) * 128, kb + p * 2048);
        for (int p = 0; p < 4; p++)
            async_cp16(vgb + (size_t)(p * 32) * 4096 + kv0, vb + p * 2048);
    };

    // softmax + T12 redistribution for one 32x32 score block (verified v8 recipe)
    auto SOFTMAX = [&](const f32x16& accS, float& ls, bf16x8& pfa, bf16x8& pfb) {
        u32 P[8];
#pragma unroll
        for (int g = 0; g < 4; g++) {
            float e0 = __builtin_amdgcn_exp2f(accS[4 * g + 0] * CEXP);
            float e1 = __builtin_amdgcn_exp2f(accS[4 * g + 1] * CEXP);
            float e2 = __builtin_amdgcn_exp2f(accS[4 * g + 2] * CEXP);
            float e3 = __builtin_amdgcn_exp2f(accS[4 * g + 3] * CEXP);
            ls += (e0 + e1) + (e2 + e3);
            P[2 * g] = cvt_pk_bf16(e0, e1);
            P[2 * g + 1] = cvt_pk_bf16(e2, e3);
        }
        u32x2 a0 = __builtin_amdgcn_permlane32_swap(P[0], P[2], false, false);
        u32x2 a1 = __builtin_amdgcn_permlane32_swap(P[1], P[3], false, false);
        u32x2 a2 = __builtin_amdgcn_permlane32_swap(P[4], P[6], false, false);
        u32x2 a3 = __builtin_amdgcn_permlane32_swap(P[5], P[7], false, false);
        union { u32 u[4]; bf16x8 v; } f0, f1;
        f0.u[0] = a0.x; f0.u[1] = a1.x; f0.u[2] = a0.y; f0.u[3] = a1.y;
        f1.u[0] = a2.x; f1.u[1] = a3.x; f1.u[2] = a2.y; f1.u[3] = a3.y;
        pfa = f0.v; pfb = f1.v;
    };

    const int NT = S >> 6;
    STAGE(0, 0);
    __syncthreads();   // drain prologue DMA (vmcnt 0) + barrier

    for (int tt = 0; tt < NT; tt++) {
        int cur = tt & 1;
        if (tt + 1 < NT) STAGE((tt + 1) * 64, cur ^ 1);
        const u16* sKc = sK0 + cur * 8192;
        const u16* sVc = sV0 + cur * 8192;

        // QK^T (swapped): D[kv_local][q], this wave's kv-half; both q-groups
        // share each K fragment read.
        f32x16 accS0 = {}, accS1 = {};
        const u16* krow = sKc + (size_t)(kvh * 32 + l31) * 128;
#pragma unroll
        for (int st = 0; st < 8; st++) {
            bf16x8 kf = *(const bf16x8*)(krow + (((st * 2 + hh) ^ lx) * 8));
            bf16x8 a1 = *(const bf16x8*)(qp1 + st * 16);
            accS0 = __builtin_amdgcn_mfma_f32_32x32x16_bf16(kf, aq0[st], accS0, 0, 0, 0);
            accS1 = __builtin_amdgcn_mfma_f32_32x32x16_bf16(kf, a1, accS1, 0, 0, 0);
        }

        bf16x8 pf0[2], pf1[2];
        SOFTMAX(accS0, lsum0, pf0[0], pf0[1]);
        SOFTMAX(accS1, lsum1, pf1[0], pf1[1]);

        // PV: O[64 q][128 d] += P[64 x 32] * V[32 x 128]; V frags shared
        // across q-groups.
#pragma unroll
        for (int db = 0; db < 4; db++) {
            const u16* vrow = sVc + (size_t)(db * 32 + l31) * 64;
#pragma unroll
            for (int ks = 0; ks < 2; ks++) {
                bf16x8 vf = *(const bf16x8*)(vrow + (((kvh * 4 + ks * 2 + hh) ^ lx) * 8));
                accO0[db] = __builtin_amdgcn_mfma_f32_32x32x16_bf16(pf0[ks], vf, accO0[db], 0, 0, 0);
                accO1[db] = __builtin_amdgcn_mfma_f32_32x32x16_bf16(pf1[ks], vf, accO1[db], 0, 0, 0);
            }
        }

        __syncthreads();  // waits vmcnt(0): next tile's DMA (hidden under compute)
    }

    // ---- combine kv-halves (pure add: static softmax), then normalize ----
    float xs[2];
    {
        float x0 = lsum0 + __shfl_xor(lsum0, 32, 64);
        float x1 = lsum1 + __shfl_xor(lsum1, 32, 64);
        xs[0] = x0; xs[1] = x1;
    }
    float* sComb = (float*)smem;              // [2 qs][4096] per round
    float* sL = (float*)(smem + 32768);       // [2 qs][32]

#pragma unroll
    for (int g = 0; g < 2; g++) {
        const f32x16* aco = (g == 0) ? accO0 : accO1;
        if (kvh == 1) {
            if (hh == 0) sL[qs * 32 + l31] = xs[g];
            float* dst = sComb + qs * 4096;
#pragma unroll
            for (int db = 0; db < 4; db++)
#pragma unroll
                for (int rr = 0; rr < 4; rr++) {
                    f32x4 part;
                    part[0] = aco[db][rr * 4 + 0];
                    part[1] = aco[db][rr * 4 + 1];
                    part[2] = aco[db][rr * 4 + 2];
                    part[3] = aco[db][rr * 4 + 3];
                    *(f32x4*)(dst + (db * 4 + rr) * 256 + lane * 4) = part;
                }
        }
        __syncthreads();
        if (kvh == 0) {
            float ltot = xs[g] + sL[qs * 32 + l31];
            float invq = 1.f / ltot;
            const float* src = sComb + qs * 4096;
#pragma unroll
            for (int db = 0; db < 4; db++)
#pragma unroll
                for (int rr = 0; rr < 4; rr++) {
                    f32x4 o = *(const f32x4*)(src + (db * 4 + rr) * 256 + lane * 4);
#pragma unroll
                    for (int p = 0; p < 4; p++) {
                        int r = rr * 4 + p;
                        int qloc = (r & 3) + 8 * (r >> 2) + 4 * hh;
                        float v = (o[p] + aco[db][r]) * __shfl(invq, qloc, 64);
                        outp[(size_t)(BS + q0w + g * 32 + qloc) * 2048 + hb * 128 + db * 32 + l31] =
                            f2bf(v);
                    }
                }
        }
        __syncthreads();
    }
}

extern "C" void kernel_launch(void* const* d_in, const int* in_sizes, int n_in,
                              void* d_out, int out_size, void* d_ws, size_t ws_size,
                              hipStream_t stream) {
    const float* q  = (const float*)d_in[0];
    const float* k  = (const float*)d_in[1];
    const float* v  = (const float*)d_in[2];
    const float* Wq = (const float*)d_in[3];
    const float* bq = (const float*)d_in[4];
    const float* Wk = (const float*)d_in[5];
    const float* bk = (const float*)d_in[6];
    const float* Wv = (const float*)d_in[7];
    const float* bv = (const float*)d_in[8];
    const float* Wo = (const float*)d_in[9];
    const float* bo = (const float*)d_in[10];
    float* out = (float*)d_out;

    const int S = 2048, D = 2048, Dh = 128, M = 4096;  // M = B*S
    const int QKV = M * D;
    const int WDD = D * D;
    const int WDH = D * Dh;
    const int MDh = M * Dh;

    u16* ws   = (u16*)d_ws;
    u16* q_bf = ws;
    u16* k_bf = q_bf + QKV;
    u16* v_bf = k_bf + QKV;
    u16* WqT  = v_bf + QKV;
    u16* WoT  = WqT + WDD;
    u16* WkT  = WoT + WDD;
    u16* WvT  = WkT + WDH;
    u16* qhb  = WvT + WDH;       // [M][2048] bf16
    u16* khb  = qhb + QKV;       // [M][128]
    u16* vhTb = khb + MDh;       // [128][M]
    u16* aout = vhTb + MDh;      // [M][2048]
    float* kacc = (float*)(aout + QKV);  // [M][128] fp32
    float* vacc = kacc + MDh;            // [M][128] fp32

    hipMemsetAsync(kacc, 0, (size_t)2 * MDh * sizeof(float), stream);

    cvt3<<<dim3(QKV / 1024, 3), 256, 0, stream>>>(q, k, v, q_bf, k_bf, v_bf);
    transpose2<<<dim3(64, 64, 2), 256, 0, stream>>>(Wq, WqT, Wo, WoT, D, D);
    transpose2<<<dim3(64, 4, 2), 256, 0, stream>>>(Wk, WkT, Wv, WvT, D, Dh);

    gemm_bt2<u16><<<dim3(256), 512, 0, stream>>>(q_bf, WqT, bq, qhb, M, D, D, D);
    gemm_kv_sk<<<dim3(32, 2, 4), 256, 0, stream>>>(k_bf, v_bf, WkT, WvT, kacc, vacc, D, 512);
    cvt_kv<<<dim3(128, 4, 2), 256, 0, stream>>>(kacc, vacc, bk, bv, khb, vhTb, M);

    mqa_attn<<<dim3(16, 16, 2), 256, 0, stream>>>(qhb, khb, vhTb, aout, S);

    gemm_bt2<float><<<dim3(256), 512, 0, stream>>>(aout, WoT, bo, out, M, D, D, D);
}

// Round 6
// 357.110 us; speedup vs baseline: 1.0278x; 1.0278x over previous
//
#include <hip/hip_runtime.h>

typedef unsigned short u16;
typedef unsigned int u32;
typedef __bf16 bf16_t;
typedef __attribute__((ext_vector_type(8))) bf16_t bf16x8;
typedef __attribute__((ext_vector_type(4))) float f32x4;
typedef __attribute__((ext_vector_type(16))) float f32x16;
typedef __attribute__((ext_vector_type(2))) unsigned int u32x2;

__device__ inline u16 f2bf(float f) {
    union { float f; u32 u; } v; v.f = f;
    u32 u = v.u;
    u32 r = (u + 0x7fffu + ((u >> 16) & 1u)) >> 16;
    return (u16)r;
}

__device__ inline u32 cvt_pk_bf16(float lo, float hi) {
    u32 r;
    asm("v_cvt_pk_bf16_f32 %0, %1, %2" : "=v"(r) : "v"(lo), "v"(hi));
    return r;
}

// async global->LDS, 16B per lane; LDS dest is wave-uniform base + lane*16
__device__ inline void async_cp16(const void* g, void* l) {
    __builtin_amdgcn_global_load_lds((const __attribute__((address_space(1))) void*)g,
                                     (__attribute__((address_space(3))) void*)l, 16, 0, 0);
}

// ---------------- fp32 -> bf16 convert, 3 arrays fused ----------------
__global__ __launch_bounds__(256) void cvt3(const float* __restrict__ a,
                                            const float* __restrict__ b,
                                            const float* __restrict__ c,
                                            u16* __restrict__ oa, u16* __restrict__ ob,
                                            u16* __restrict__ oc) {
    int z = blockIdx.y;
    const float* in = z == 0 ? a : (z == 1 ? b : c);
    u16* out = z == 0 ? oa : (z == 1 ? ob : oc);
    int i = (blockIdx.x * 256 + threadIdx.x) * 4;
    float4 f = *(const float4*)(in + i);
    ushort4 o;
    o.x = f2bf(f.x); o.y = f2bf(f.y); o.z = f2bf(f.z); o.w = f2bf(f.w);
    *(ushort4*)(out + i) = o;
}

// ---------------- W[K][N] fp32 -> WT[N][K] bf16, 2 matrices fused ----------------
__global__ __launch_bounds__(256) void transpose2(const float* __restrict__ W0,
                                                  u16* __restrict__ T0,
                                                  const float* __restrict__ W1,
                                                  u16* __restrict__ T1,
                                                  int K, int N) {
    const float* W = blockIdx.z == 0 ? W0 : W1;
    u16* WT = blockIdx.z == 0 ? T0 : T1;
    __shared__ float tile[32][33];
    int tr0 = blockIdx.x * 32;
    int tc0 = blockIdx.y * 32;
    int t = threadIdx.x;
    for (int i = 0; i < 4; i++) {
        int idx = t + i * 256; int r = idx >> 5, c = idx & 31;
        tile[r][c] = W[(size_t)(tr0 + r) * N + tc0 + c];
    }
    __syncthreads();
    for (int i = 0; i < 4; i++) {
        int idx = t + i * 256; int r = idx >> 5, c = idx & 31;
        WT[(size_t)(tc0 + r) * K + tr0 + c] = f2bf(tile[c][r]);
    }
}

// ---------------- big-GEMM v4: 128^2 tile, BK=64, dbuf LDS, 2 blocks/CU ----------------
// Diagnosis of v3 (triple-buffer, 144 KB LDS): 1 block/CU -> every barrier
// stall idles the whole CU; source pipelining can't hide it (m131-m141).
// v4 restores the proven mechanism: implicit cross-block overlap. 64 KB LDS
// (2 bufs x (A[128][64] + B[128][64])) -> 2 blocks/CU; grid 32x16 = 512 = 2/CU.
// 4 waves (2x2), wave tile 64x64: per K-tile 16 ds_read_b128 (each fragment
// read ONCE; v3 re-read B-frags per row-half) + 32 MFMA. v7-attn schedule:
// STAGE(t+1, buf^1) -> frag reads -> MFMA (setprio) -> __syncthreads (its
// vmcnt0 drain is covered by the co-resident block). Chunk-XOR swizzle on
// both sides (rule 21). XCD 2D chunk: 8x8-tile regions (4MB A + 4MB B / XCD).
template <typename OUT_T>
__global__ __launch_bounds__(256, 2) void gemm_bt3(const u16* __restrict__ A,
                                                   const u16* __restrict__ BT,
                                                   const float* __restrict__ bias,
                                                   OUT_T* __restrict__ C,
                                                   int M, int N, int K, int ldout) {
    __shared__ u16 smem[2 * 16384];     // 64 KB
    int t = threadIdx.x, lane = t & 63, wv = t >> 6;
    int quad = lane >> 4, c16 = lane & 15;
    int rx = c16 & 7;
    int wr = wv >> 1, wc = wv & 1;      // wave tile origin (wr*64, wc*64)

    // XCD 2D chunk: 32 m-tiles x 16 n-tiles; 8 XCDs = 4x2 regions of 8x8 tiles
    int bid = blockIdx.x;
    int xcd = bid & 7, loc = bid >> 3;                 // loc 0..63
    int bm = (((xcd >> 1) << 3) + (loc & 7)) << 7;     // m-tile 0..31
    int bn = (((xcd & 1) << 3) + (loc >> 3)) << 7;     // n-tile 0..15

    f32x4 acc[4][4] = {};

    // staging: wave covers rows p*32 + wv*8 + (lane>>3), chunk lane&7,
    // global src chunk pre-XOR'd by row&7 ((srow+32p)&7 == srow&7)
    int srow = wv * 8 + (lane >> 3);
    int scol = ((lane & 7) ^ (srow & 7)) * 8;
    const u16* Ag = A + (size_t)(bm + srow) * K + scol;
    const u16* Bg = BT + (size_t)(bn + srow) * K + scol;
    u16* ad0 = smem + (wv * 8) * 64;
    u16* bd0 = smem + 8192 + (wv * 8) * 64;

    auto STAGE = [&](int kt, int d) {
        u16* ad = ad0 + d * 16384;
        u16* bd = bd0 + d * 16384;
        const u16* ag = Ag + (size_t)kt * 64;
        const u16* bg = Bg + (size_t)kt * 64;
        for (int p = 0; p < 4; p++)
            async_cp16(ag + (size_t)(p * 32) * K, ad + p * 2048);
        for (int p = 0; p < 4; p++)
            async_cp16(bg + (size_t)(p * 32) * K, bd + p * 2048);
    };

    const int NT = K >> 6;
    STAGE(0, 0);
    __syncthreads();

    for (int tt = 0; tt < NT; tt++) {
        int cur = tt & 1;
        if (tt + 1 < NT) STAGE(tt + 1, cur ^ 1);
        const u16* sA = smem + cur * 16384;
        const u16* sB = sA + 8192;

        bf16x8 af[4][2], bf[4][2];
        for (int mi = 0; mi < 4; mi++)
            for (int kk = 0; kk < 2; kk++)
                af[mi][kk] = *(const bf16x8*)&sA[(wr * 64 + mi * 16 + c16) * 64 +
                                                 (((kk * 4 + quad) ^ rx) * 8)];
        for (int ni = 0; ni < 4; ni++)
            for (int kk = 0; kk < 2; kk++)
                bf[ni][kk] = *(const bf16x8*)&sB[(wc * 64 + ni * 16 + c16) * 64 +
                                                 (((kk * 4 + quad) ^ rx) * 8)];
        __builtin_amdgcn_s_setprio(1);
        for (int kk = 0; kk < 2; kk++)
            for (int mi = 0; mi < 4; mi++)
                for (int ni = 0; ni < 4; ni++)
                    acc[mi][ni] = __builtin_amdgcn_mfma_f32_16x16x32_bf16(
                        af[mi][kk], bf[ni][kk], acc[mi][ni], 0, 0, 0);
        __builtin_amdgcn_s_setprio(0);
        __syncthreads();   // drains next tile's DMA (hidden under compute + co-block)
    }

    for (int mi = 0; mi < 4; mi++) {
        for (int ni = 0; ni < 4; ni++) {
            int col = bn + wc * 64 + ni * 16 + c16;
            float bv = bias[col];
            for (int p = 0; p < 4; p++) {
                int row = bm + wr * 64 + mi * 16 + quad * 4 + p;
                float v = acc[mi][ni][p] + bv;
                size_t off = (size_t)row * ldout + col;
                if constexpr (__is_same(OUT_T, u16)) C[off] = f2bf(v);
                else C[off] = v;
            }
        }
    }
}

// ---------------- K/V projection, split-K with fp32 atomic partials ----------------
__global__ __launch_bounds__(256) void gemm_kv_sk(const u16* __restrict__ kbf,
                                                  const u16* __restrict__ vbf,
                                                  const u16* __restrict__ WkT,
                                                  const u16* __restrict__ WvT,
                                                  float* __restrict__ kacc,
                                                  float* __restrict__ vacc,
                                                  int K, int KS) {
    bool isv = blockIdx.y == 1;
    const u16* A = isv ? vbf : kbf;
    const u16* BT = isv ? WvT : WkT;
    float* aco = isv ? vacc : kacc;
    __shared__ u16 sA[128 * 32];
    __shared__ u16 sB[128 * 32];
    int t = threadIdx.x, lane = t & 63, wv = t >> 6;
    int quad = lane >> 4, c16 = lane & 15;
    int bm = blockIdx.x * 128;
    int wm = (wv & 1) * 64, wn = (wv >> 1) * 64;
    f32x4 acc[4][4] = {};

    int srow = wv * 32 + (lane >> 2);
    int scol = (lane & 3) * 8;
    const u16* Ag = A + (size_t)(bm + srow) * K + scol;
    const u16* Bg = BT + (size_t)srow * K + scol;
    u16* sAd = &sA[(wv * 32) * 32];
    u16* sBd = &sB[(wv * 32) * 32];

    int kbeg = blockIdx.z * KS;
    for (int k0 = kbeg; k0 < kbeg + KS; k0 += 32) {
        __syncthreads();
        async_cp16(Ag + k0, sAd);
        async_cp16(Ag + (size_t)16 * K + k0, sAd + 16 * 32);
        async_cp16(Bg + k0, sBd);
        async_cp16(Bg + (size_t)16 * K + k0, sBd + 16 * 32);
        __syncthreads();
        bf16x8 af[4], bfr[4];
        for (int mi = 0; mi < 4; mi++)
            af[mi] = *(const bf16x8*)&sA[(wm + mi * 16 + c16) * 32 + quad * 8];
        for (int ni = 0; ni < 4; ni++)
            bfr[ni] = *(const bf16x8*)&sB[(wn + ni * 16 + c16) * 32 + quad * 8];
        for (int mi = 0; mi < 4; mi++)
            for (int ni = 0; ni < 4; ni++)
                acc[mi][ni] = __builtin_amdgcn_mfma_f32_16x16x32_bf16(
                    af[mi], bfr[ni], acc[mi][ni], 0, 0, 0);
    }

    for (int mi = 0; mi < 4; mi++)
        for (int ni = 0; ni < 4; ni++) {
            int col = wn + ni * 16 + c16;
            for (int p = 0; p < 4; p++) {
                int row = bm + wm + mi * 16 + quad * 4 + p;
                atomicAdd(&aco[(size_t)row * 128 + col], acc[mi][ni][p]);
            }
        }
}

// ---------------- kv epilogue: +bias, ->bf16; z=0: khb copy; z=1: vhT transpose ----------------
__global__ __launch_bounds__(256) void cvt_kv(const float* __restrict__ kacc,
                                              const float* __restrict__ vacc,
                                              const float* __restrict__ bk,
                                              const float* __restrict__ bv,
                                              u16* __restrict__ khb,
                                              u16* __restrict__ vhT,
                                              int M) {
    int t = threadIdx.x;
    int tr0 = blockIdx.x * 32;
    int tc0 = blockIdx.y * 32;
    if (blockIdx.z == 0) {
        for (int i = 0; i < 4; i++) {
            int idx = t + i * 256; int r = idx >> 5, c = idx & 31;
            khb[(size_t)(tr0 + r) * 128 + tc0 + c] =
                f2bf(kacc[(size_t)(tr0 + r) * 128 + tc0 + c] + bk[tc0 + c]);
        }
    } else {
        __shared__ float tile[32][33];
        for (int i = 0; i < 4; i++) {
            int idx = t + i * 256; int r = idx >> 5, c = idx & 31;
            tile[r][c] = vacc[(size_t)(tr0 + r) * 128 + tc0 + c] + bv[tc0 + c];
        }
        __syncthreads();
        for (int i = 0; i < 4; i++) {
            int idx = t + i * 256; int r = idx >> 5, c = idx & 31;
            vhT[(size_t)(tc0 + r) * M + tr0 + c] = f2bf(tile[c][r]);
        }
    }
}

// ---------------- flash attention v8 (reverted from v9): 32x32 MFMA, P in regs ----------------
// v9 (64q x 32kv, Q-reload from global) regressed 84.9 -> 94.4 us: attn is
// latency-chain-bound; putting VMEM Q loads in the QK chain lengthened the
// critical path even though LDS conflicts halved. v8 restored verbatim.
__global__ __launch_bounds__(256, 2) void mqa_attn(const u16* __restrict__ qh,   // [B*S][2048]
                                                   const u16* __restrict__ kh,   // [B*S][128]
                                                   const u16* __restrict__ vhT,  // [128][B*S]
                                                   u16* __restrict__ outp,      // [B*S][2048]
                                                   int S) {
    constexpr float CEXP = 0.08838834764831845f * 1.4426950408889634f;  // scale * log2(e)
    __shared__ u16 smem[32768];           // 65536 B
    u16* sK0 = smem;                      // 2 bufs x 8192 u16 ([64][128])
    u16* sV0 = smem + 16384;              // 2 bufs x 8192 u16 ([128][64])

    int t = threadIdx.x, lane = t & 63, wv = t >> 6;
    int l31 = lane & 31, hh = lane >> 5;
    int lx = l31 & 7;                     // row-XOR for swizzled frag reads
    int b = blockIdx.z, hb = blockIdx.y;
    int q0w = blockIdx.x * 128 + wv * 32;
    int BS = b * S;

    // Q frags (B-operand): lane holds Q[q0w + l31][st*16 + hh*8 + j]
    bf16x8 aq[8];
    {
        const u16* qp = qh + (size_t)(BS + q0w + l31) * 2048 + hb * 128 + hh * 8;
#pragma unroll
        for (int st = 0; st < 8; st++) aq[st] = *(const bf16x8*)(qp + st * 16);
    }

    f32x16 accO[4] = {};   // O[q=(r&3)+8(r>>2)+4hh][d=db*32+l31]
    float lsum = 0.f;

    // ---- staging geometry (pre-swizzled global source, linear LDS dest) ----
    int ksub = lane >> 4, kch = lane & 15;
    int klx = (wv * 4 + ksub) & 7;
    const u16* kgb = kh + (size_t)(BS + wv * 4 + ksub) * 128 + ((kch ^ klx) * 8);
    int vsub = lane >> 3, vch = lane & 7;
    int vlx = vsub & 7;
    const u16* vgb = vhT + (size_t)(wv * 8 + vsub) * 4096 + BS + ((vch ^ vlx) * 8);

    u16* kb0 = sK0 + (wv * 4) * 128;      // + buf*8192 + p*2048
    u16* vb0 = sV0 + (wv * 8) * 64;       // + buf*8192 + p*2048

    auto STAGE = [&](int kv0, int d) {
        u16* kb = kb0 + d * 8192;
        u16* vb = vb0 + d * 8192;
        for (int p = 0; p < 4; p++)
            async_cp16(kgb + (size_t)(kv0 + p * 16) * 128, kb + p * 2048);
        for (int p = 0; p < 4; p++)
            async_cp16(vgb + (size_t)(p * 32) * 4096 + kv0, vb + p * 2048);
    };

    const int NT = S >> 6;
    STAGE(0, 0);
    __syncthreads();   // drain prologue DMA (vmcnt 0) + barrier

    for (int tt = 0; tt < NT; tt++) {
        int cur = tt & 1;
        if (tt + 1 < NT) STAGE((tt + 1) * 64, cur ^ 1);
        const u16* sKc = sK0 + cur * 8192;
        const u16* sVc = sV0 + cur * 8192;

        bf16x8 pf[4];   // PV A-frags, ksteps of 16 kv
#pragma unroll
        for (int sub = 0; sub < 2; sub++) {
            // QK^T (swapped): D[kv_local][q], kv subtile sub
            f32x16 accS = {};
            const u16* krow = sKc + (size_t)(sub * 32 + l31) * 128;
#pragma unroll
            for (int st = 0; st < 8; st++) {
                bf16x8 kf = *(const bf16x8*)(krow + (((st * 2 + hh) ^ lx) * 8));
                accS = __builtin_amdgcn_mfma_f32_32x32x16_bf16(kf, aq[st], accS, 0, 0, 0);
            }
            // static softmax: e = exp2(s*CEXP); pack pairs to bf16 (RNE)
            u32 P[8];
#pragma unroll
            for (int g = 0; g < 4; g++) {
                float e0 = __builtin_amdgcn_exp2f(accS[4 * g + 0] * CEXP);
                float e1 = __builtin_amdgcn_exp2f(accS[4 * g + 1] * CEXP);
                float e2 = __builtin_amdgcn_exp2f(accS[4 * g + 2] * CEXP);
                float e3 = __builtin_amdgcn_exp2f(accS[4 * g + 3] * CEXP);
                P[2 * g] = cvt_pk_bf16(e0, e1);
                P[2 * g + 1] = cvt_pk_bf16(e2, e3);
            }
            // l summed from the SAME rounded bf16 that feeds PV (bias cancels)
#pragma unroll
            for (int w = 0; w < 8; w++) {
                union { u32 u; float f; } lo, hi;
                lo.u = P[w] << 16;
                hi.u = P[w] & 0xffff0000u;
                lsum += lo.f + hi.f;
            }
            // permlane32_swap: exchange half-rows between lane l and l^32
            u32x2 a0 = __builtin_amdgcn_permlane32_swap(P[0], P[2], false, false);
            u32x2 a1 = __builtin_amdgcn_permlane32_swap(P[1], P[3], false, false);
            u32x2 a2 = __builtin_amdgcn_permlane32_swap(P[4], P[6], false, false);
            u32x2 a3 = __builtin_amdgcn_permlane32_swap(P[5], P[7], false, false);
            union { u32 u[4]; bf16x8 v; } f0, f1;
            f0.u[0] = a0.x; f0.u[1] = a1.x; f0.u[2] = a0.y; f0.u[3] = a1.y;
            f1.u[0] = a2.x; f1.u[1] = a3.x; f1.u[2] = a2.y; f1.u[3] = a3.y;
            pf[sub * 2] = f0.v;
            pf[sub * 2 + 1] = f1.v;
        }

        // PV: O[32 q][128 d] += P[32 x 64] * V[64 x 128]
#pragma unroll
        for (int db = 0; db < 4; db++) {
            const u16* vrow = sVc + (size_t)(db * 32 + l31) * 64;
#pragma unroll
            for (int ks = 0; ks < 4; ks++) {
                bf16x8 vf = *(const bf16x8*)(vrow + (((ks * 2 + hh) ^ lx) * 8));
                accO[db] = __builtin_amdgcn_mfma_f32_32x32x16_bf16(pf[ks], vf, accO[db], 0, 0, 0);
            }
        }

        __syncthreads();  // waits vmcnt(0): next tile's DMA (hidden under compute)
    }

    // ---- epilogue: combine half-sums, normalize, store ----
    lsum += __shfl_xor(lsum, 32, 64);    // lanes q and q+32 both hold denom(q=l31)
    float invq = 1.f / lsum;
    float inv[16];
#pragma unroll
    for (int r = 0; r < 16; r++) {
        int qloc = (r & 3) + 8 * (r >> 2) + 4 * hh;
        inv[r] = __shfl(invq, qloc, 64);
    }
#pragma unroll
    for (int db = 0; db < 4; db++) {
#pragma unroll
        for (int r = 0; r < 16; r++) {
            int qloc = (r & 3) + 8 * (r >> 2) + 4 * hh;
            outp[(size_t)(BS + q0w + qloc) * 2048 + hb * 128 + db * 32 + l31] =
                f2bf(accO[db][r] * inv[r]);
        }
    }
}

extern "C" void kernel_launch(void* const* d_in, const int* in_sizes, int n_in,
                              void* d_out, int out_size, void* d_ws, size_t ws_size,
                              hipStream_t stream) {
    const float* q  = (const float*)d_in[0];
    const float* k  = (const float*)d_in[1];
    const float* v  = (const float*)d_in[2];
    const float* Wq = (const float*)d_in[3];
    const float* bq = (const float*)d_in[4];
    const float* Wk = (const float*)d_in[5];
    const float* bk = (const float*)d_in[6];
    const float* Wv = (const float*)d_in[7];
    const float* bv = (const float*)d_in[8];
    const float* Wo = (const float*)d_in[9];
    const float* bo = (const float*)d_in[10];
    float* out = (float*)d_out;

    const int S = 2048, D = 2048, Dh = 128, M = 4096;  // M = B*S
    const int QKV = M * D;
    const int WDD = D * D;
    const int WDH = D * Dh;
    const int MDh = M * Dh;

    u16* ws   = (u16*)d_ws;
    u16* q_bf = ws;
    u16* k_bf = q_bf + QKV;
    u16* v_bf = k_bf + QKV;
    u16* WqT  = v_bf + QKV;
    u16* WoT  = WqT + WDD;
    u16* WkT  = WoT + WDD;
    u16* WvT  = WkT + WDH;
    u16* qhb  = WvT + WDH;       // [M][2048] bf16
    u16* khb  = qhb + QKV;       // [M][128]
    u16* vhTb = khb + MDh;       // [128][M]
    u16* aout = vhTb + MDh;      // [M][2048]
    float* kacc = (float*)(aout + QKV);  // [M][128] fp32
    float* vacc = kacc + MDh;            // [M][128] fp32

    hipMemsetAsync(kacc, 0, (size_t)2 * MDh * sizeof(float), stream);

    cvt3<<<dim3(QKV / 1024, 3), 256, 0, stream>>>(q, k, v, q_bf, k_bf, v_bf);
    transpose2<<<dim3(64, 64, 2), 256, 0, stream>>>(Wq, WqT, Wo, WoT, D, D);
    transpose2<<<dim3(64, 4, 2), 256, 0, stream>>>(Wk, WkT, Wv, WvT, D, Dh);

    gemm_bt3<u16><<<dim3(512), 256, 0, stream>>>(q_bf, WqT, bq, qhb, M, D, D, D);
    gemm_kv_sk<<<dim3(32, 2, 4), 256, 0, stream>>>(k_bf, v_bf, WkT, WvT, kacc, vacc, D, 512);
    cvt_kv<<<dim3(128, 4, 2), 256, 0, stream>>>(kacc, vacc, bk, bv, khb, vhTb, M);

    mqa_attn<<<dim3(16, 16, 2), 256, 0, stream>>>(qhb, khb, vhTb, aout, S);

    gemm_bt3<float><<<dim3(512), 256, 0, stream>>>(aout, WoT, bo, out, M, D, D, D);
}

// Round 8
// 346.682 us; speedup vs baseline: 1.0588x; 1.0301x over previous
//
#include <hip/hip_runtime.h>

typedef unsigned short u16;
typedef unsigned int u32;
typedef __bf16 bf16_t;
typedef __attribute__((ext_vector_type(8))) bf16_t bf16x8;
typedef __attribute__((ext_vector_type(4))) float f32x4;
typedef __attribute__((ext_vector_type(16))) float f32x16;
typedef __attribute__((ext_vector_type(2))) unsigned int u32x2;

__device__ inline u16 f2bf(float f) {
    union { float f; u32 u; } v; v.f = f;
    u32 u = v.u;
    u32 r = (u + 0x7fffu + ((u >> 16) & 1u)) >> 16;
    return (u16)r;
}

__device__ inline u32 cvt_pk_bf16(float lo, float hi) {
    u32 r;
    asm("v_cvt_pk_bf16_f32 %0, %1, %2" : "=v"(r) : "v"(lo), "v"(hi));
    return r;
}

// async global->LDS, 16B per lane; LDS dest is wave-uniform base + lane*16
__device__ inline void async_cp16(const void* g, void* l) {
    __builtin_amdgcn_global_load_lds((const __attribute__((address_space(1))) void*)g,
                                     (__attribute__((address_space(3))) void*)l, 16, 0, 0);
}

// ---------------- prep: fused cvt3 + transpose2(Wq,Wo) + transpose2(Wk,Wv) + memset ----------------
// One launch replaces 4 (memset, cvt3, 2x transpose2): removes 3 launch gaps
// and lets the tiny transpose grids ride along the big cvt grid.
// Block ranges: [0,24576) cvt3 | [24576,32768) Wq/Wo transpose |
// [32768,33280) Wk/Wv transpose | [33280,34304) zero kacc/vacc.
__global__ __launch_bounds__(256) void prep(const float* __restrict__ q,
                                            const float* __restrict__ k,
                                            const float* __restrict__ v,
                                            u16* __restrict__ q_bf, u16* __restrict__ k_bf,
                                            u16* __restrict__ v_bf,
                                            const float* __restrict__ Wq, u16* __restrict__ WqT,
                                            const float* __restrict__ Wo, u16* __restrict__ WoT,
                                            const float* __restrict__ Wk, u16* __restrict__ WkT,
                                            const float* __restrict__ Wv, u16* __restrict__ WvT,
                                            float* __restrict__ zacc) {
    int bid = blockIdx.x, t = threadIdx.x;
    if (bid < 24576) {
        int z = bid >> 13, x = bid & 8191;
        const float* in = z == 0 ? q : (z == 1 ? k : v);
        u16* out = z == 0 ? q_bf : (z == 1 ? k_bf : v_bf);
        int i = (x * 256 + t) * 4;
        float4 f = *(const float4*)(in + i);
        ushort4 o;
        o.x = f2bf(f.x); o.y = f2bf(f.y); o.z = f2bf(f.z); o.w = f2bf(f.w);
        *(ushort4*)(out + i) = o;
    } else if (bid < 33280) {
        // W[K][N] -> WT[N][K] bf16
        const float* W; u16* WT; int K, N, bx, by;
        if (bid < 32768) {
            int idx = bid - 24576;              // 8192 = 2 x 64 x 64
            W = (idx >> 12) ? Wo : Wq; WT = (idx >> 12) ? WoT : WqT;
            K = 2048; N = 2048;
            int rem = idx & 4095; bx = rem >> 6; by = rem & 63;
        } else {
            int idx = bid - 32768;              // 512 = 2 x 64 x 4
            W = (idx >> 8) ? Wv : Wk; WT = (idx >> 8) ? WvT : WkT;
            K = 2048; N = 128;
            int rem = idx & 255; bx = rem >> 2; by = rem & 3;
        }
        __shared__ float tile[32][33];
        int tr0 = bx * 32, tc0 = by * 32;
        for (int i = 0; i < 4; i++) {
            int idx = t + i * 256; int r = idx >> 5, c = idx & 31;
            tile[r][c] = W[(size_t)(tr0 + r) * N + tc0 + c];
        }
        __syncthreads();
        for (int i = 0; i < 4; i++) {
            int idx = t + i * 256; int r = idx >> 5, c = idx & 31;
            WT[(size_t)(tc0 + r) * K + tr0 + c] = f2bf(tile[c][r]);
        }
    } else {
        int idx = bid - 33280;                  // 1024 blocks x 1024 floats = 2*MDh
        float4 z4 = make_float4(0.f, 0.f, 0.f, 0.f);
        *(float4*)(zacc + (size_t)(idx * 256 + t) * 4) = z4;
    }
}

// ---------------- big-GEMM v4: 128^2 tile, BK=64, dbuf LDS, 2 blocks/CU ----------------
// 2-phase minimum schedule (T3 recipe): STAGE(t+1) -> frag reads -> MFMA
// (setprio) -> single __syncthreads per K-tile; implicit cross-block overlap
// at 2 blocks/CU hides the barrier drain. Chunk-XOR swizzle both sides.
template <typename OUT_T>
__global__ __launch_bounds__(256, 2) void gemm_bt3(const u16* __restrict__ A,
                                                   const u16* __restrict__ BT,
                                                   const float* __restrict__ bias,
                                                   OUT_T* __restrict__ C,
                                                   int M, int N, int K, int ldout) {
    __shared__ u16 smem[2 * 16384];     // 64 KB
    int t = threadIdx.x, lane = t & 63, wv = t >> 6;
    int quad = lane >> 4, c16 = lane & 15;
    int rx = c16 & 7;
    int wr = wv >> 1, wc = wv & 1;      // wave tile origin (wr*64, wc*64)

    // XCD 2D chunk: 32 m-tiles x 16 n-tiles; 8 XCDs = 4x2 regions of 8x8 tiles
    int bid = blockIdx.x;
    int xcd = bid & 7, loc = bid >> 3;                 // loc 0..63
    int bm = (((xcd >> 1) << 3) + (loc & 7)) << 7;     // m-tile 0..31
    int bn = (((xcd & 1) << 3) + (loc >> 3)) << 7;     // n-tile 0..15

    f32x4 acc[4][4] = {};

    int srow = wv * 8 + (lane >> 3);
    int scol = ((lane & 7) ^ (srow & 7)) * 8;
    const u16* Ag = A + (size_t)(bm + srow) * K + scol;
    const u16* Bg = BT + (size_t)(bn + srow) * K + scol;
    u16* ad0 = smem + (wv * 8) * 64;
    u16* bd0 = smem + 8192 + (wv * 8) * 64;

    auto STAGE = [&](int kt, int d) {
        u16* ad = ad0 + d * 16384;
        u16* bd = bd0 + d * 16384;
        const u16* ag = Ag + (size_t)kt * 64;
        const u16* bg = Bg + (size_t)kt * 64;
        for (int p = 0; p < 4; p++)
            async_cp16(ag + (size_t)(p * 32) * K, ad + p * 2048);
        for (int p = 0; p < 4; p++)
            async_cp16(bg + (size_t)(p * 32) * K, bd + p * 2048);
    };

    const int NT = K >> 6;
    STAGE(0, 0);
    __syncthreads();

    for (int tt = 0; tt < NT; tt++) {
        int cur = tt & 1;
        if (tt + 1 < NT) STAGE(tt + 1, cur ^ 1);
        const u16* sA = smem + cur * 16384;
        const u16* sB = sA + 8192;

        bf16x8 af[4][2], bf[4][2];
        for (int mi = 0; mi < 4; mi++)
            for (int kk = 0; kk < 2; kk++)
                af[mi][kk] = *(const bf16x8*)&sA[(wr * 64 + mi * 16 + c16) * 64 +
                                                 (((kk * 4 + quad) ^ rx) * 8)];
        for (int ni = 0; ni < 4; ni++)
            for (int kk = 0; kk < 2; kk++)
                bf[ni][kk] = *(const bf16x8*)&sB[(wc * 64 + ni * 16 + c16) * 64 +
                                                 (((kk * 4 + quad) ^ rx) * 8)];
        __builtin_amdgcn_s_setprio(1);
        for (int kk = 0; kk < 2; kk++)
            for (int mi = 0; mi < 4; mi++)
                for (int ni = 0; ni < 4; ni++)
                    acc[mi][ni] = __builtin_amdgcn_mfma_f32_16x16x32_bf16(
                        af[mi][kk], bf[ni][kk], acc[mi][ni], 0, 0, 0);
        __builtin_amdgcn_s_setprio(0);
        __syncthreads();   // drains next tile's DMA (hidden under compute + co-block)
    }

    for (int mi = 0; mi < 4; mi++) {
        for (int ni = 0; ni < 4; ni++) {
            int col = bn + wc * 64 + ni * 16 + c16;
            float bv = bias[col];
            for (int p = 0; p < 4; p++) {
                int row = bm + wr * 64 + mi * 16 + quad * 4 + p;
                float v = acc[mi][ni][p] + bv;
                size_t off = (size_t)row * ldout + col;
                if constexpr (__is_same(OUT_T, u16)) C[off] = f2bf(v);
                else C[off] = v;
            }
        }
    }
}

// ---------------- K/V projection, split-K with fp32 atomic partials ----------------
__global__ __launch_bounds__(256) void gemm_kv_sk(const u16* __restrict__ kbf,
                                                  const u16* __restrict__ vbf,
                                                  const u16* __restrict__ WkT,
                                                  const u16* __restrict__ WvT,
                                                  float* __restrict__ kacc,
                                                  float* __restrict__ vacc,
                                                  int K, int KS) {
    bool isv = blockIdx.y == 1;
    const u16* A = isv ? vbf : kbf;
    const u16* BT = isv ? WvT : WkT;
    float* aco = isv ? vacc : kacc;
    __shared__ u16 sA[128 * 32];
    __shared__ u16 sB[128 * 32];
    int t = threadIdx.x, lane = t & 63, wv = t >> 6;
    int quad = lane >> 4, c16 = lane & 15;
    int bm = blockIdx.x * 128;
    int wm = (wv & 1) * 64, wn = (wv >> 1) * 64;
    f32x4 acc[4][4] = {};

    int srow = wv * 32 + (lane >> 2);
    int scol = (lane & 3) * 8;
    const u16* Ag = A + (size_t)(bm + srow) * K + scol;
    const u16* Bg = BT + (size_t)srow * K + scol;
    u16* sAd = &sA[(wv * 32) * 32];
    u16* sBd = &sB[(wv * 32) * 32];

    int kbeg = blockIdx.z * KS;
    for (int k0 = kbeg; k0 < kbeg + KS; k0 += 32) {
        __syncthreads();
        async_cp16(Ag + k0, sAd);
        async_cp16(Ag + (size_t)16 * K + k0, sAd + 16 * 32);
        async_cp16(Bg + k0, sBd);
        async_cp16(Bg + (size_t)16 * K + k0, sBd + 16 * 32);
        __syncthreads();
        bf16x8 af[4], bfr[4];
        for (int mi = 0; mi < 4; mi++)
            af[mi] = *(const bf16x8*)&sA[(wm + mi * 16 + c16) * 32 + quad * 8];
        for (int ni = 0; ni < 4; ni++)
            bfr[ni] = *(const bf16x8*)&sB[(wn + ni * 16 + c16) * 32 + quad * 8];
        for (int mi = 0; mi < 4; mi++)
            for (int ni = 0; ni < 4; ni++)
                acc[mi][ni] = __builtin_amdgcn_mfma_f32_16x16x32_bf16(
                    af[mi], bfr[ni], acc[mi][ni], 0, 0, 0);
    }

    for (int mi = 0; mi < 4; mi++)
        for (int ni = 0; ni < 4; ni++) {
            int col = wn + ni * 16 + c16;
            for (int p = 0; p < 4; p++) {
                int row = bm + wm + mi * 16 + quad * 4 + p;
                atomicAdd(&aco[(size_t)row * 128 + col], acc[mi][ni][p]);
            }
        }
}

// ---------------- kv epilogue: +bias, ->bf16; z=0: khb copy; z=1: vhT transpose ----------------
__global__ __launch_bounds__(256) void cvt_kv(const float* __restrict__ kacc,
                                              const float* __restrict__ vacc,
                                              const float* __restrict__ bk,
                                              const float* __restrict__ bv,
                                              u16* __restrict__ khb,
                                              u16* __restrict__ vhT,
                                              int M) {
    int t = threadIdx.x;
    int tr0 = blockIdx.x * 32;
    int tc0 = blockIdx.y * 32;
    if (blockIdx.z == 0) {
        for (int i = 0; i < 4; i++) {
            int idx = t + i * 256; int r = idx >> 5, c = idx & 31;
            khb[(size_t)(tr0 + r) * 128 + tc0 + c] =
                f2bf(kacc[(size_t)(tr0 + r) * 128 + tc0 + c] + bk[tc0 + c]);
        }
    } else {
        __shared__ float tile[32][33];
        for (int i = 0; i < 4; i++) {
            int idx = t + i * 256; int r = idx >> 5, c = idx & 31;
            tile[r][c] = vacc[(size_t)(tr0 + r) * 128 + tc0 + c] + bv[tc0 + c];
        }
        __syncthreads();
        for (int i = 0; i < 4; i++) {
            int idx = t + i * 256; int r = idx >> 5, c = idx & 31;
            vhT[(size_t)(tc0 + r) * M + tr0 + c] = f2bf(tile[c][r]);
        }
    }
}

// ---------------- flash attention v10: v8 + direct e-sum (lsum unpack removed) ----------------
// VALU accounting: the lsum unpack (32 shifts + 32 ands + 32 adds per
// iter/wave) was the largest VALU block in the softmax. Direct fp32 e-sum
// (validated in v9's run: identical absmax) replaces it with 8 adds.
// Everything else identical to v8 (84.0 us measured).
__global__ __launch_bounds__(256, 2) void mqa_attn(const u16* __restrict__ qh,   // [B*S][2048]
                                                   const u16* __restrict__ kh,   // [B*S][128]
                                                   const u16* __restrict__ vhT,  // [128][B*S]
                                                   u16* __restrict__ outp,      // [B*S][2048]
                                                   int S) {
    constexpr float CEXP = 0.08838834764831845f * 1.4426950408889634f;  // scale * log2(e)
    __shared__ u16 smem[32768];           // 65536 B
    u16* sK0 = smem;                      // 2 bufs x 8192 u16 ([64][128])
    u16* sV0 = smem + 16384;              // 2 bufs x 8192 u16 ([128][64])

    int t = threadIdx.x, lane = t & 63, wv = t >> 6;
    int l31 = lane & 31, hh = lane >> 5;
    int lx = l31 & 7;                     // row-XOR for swizzled frag reads
    int b = blockIdx.z, hb = blockIdx.y;
    int q0w = blockIdx.x * 128 + wv * 32;
    int BS = b * S;

    // Q frags (B-operand): lane holds Q[q0w + l31][st*16 + hh*8 + j]
    bf16x8 aq[8];
    {
        const u16* qp = qh + (size_t)(BS + q0w + l31) * 2048 + hb * 128 + hh * 8;
#pragma unroll
        for (int st = 0; st < 8; st++) aq[st] = *(const bf16x8*)(qp + st * 16);
    }

    f32x16 accO[4] = {};   // O[q=(r&3)+8(r>>2)+4hh][d=db*32+l31]
    float lsum = 0.f;

    // ---- staging geometry (pre-swizzled global source, linear LDS dest) ----
    int ksub = lane >> 4, kch = lane & 15;
    int klx = (wv * 4 + ksub) & 7;
    const u16* kgb = kh + (size_t)(BS + wv * 4 + ksub) * 128 + ((kch ^ klx) * 8);
    int vsub = lane >> 3, vch = lane & 7;
    int vlx = vsub & 7;
    const u16* vgb = vhT + (size_t)(wv * 8 + vsub) * 4096 + BS + ((vch ^ vlx) * 8);

    u16* kb0 = sK0 + (wv * 4) * 128;      // + buf*8192 + p*2048
    u16* vb0 = sV0 + (wv * 8) * 64;       // + buf*8192 + p*2048

    auto STAGE = [&](int kv0, int d) {
        u16* kb = kb0 + d * 8192;
        u16* vb = vb0 + d * 8192;
        for (int p = 0; p < 4; p++)
            async_cp16(kgb + (size_t)(kv0 + p * 16) * 128, kb + p * 2048);
        for (int p = 0; p < 4; p++)
            async_cp16(vgb + (size_t)(p * 32) * 4096 + kv0, vb + p * 2048);
    };

    const int NT = S >> 6;
    STAGE(0, 0);
    __syncthreads();   // drain prologue DMA (vmcnt 0) + barrier

    for (int tt = 0; tt < NT; tt++) {
        int cur = tt & 1;
        if (tt + 1 < NT) STAGE((tt + 1) * 64, cur ^ 1);
        const u16* sKc = sK0 + cur * 8192;
        const u16* sVc = sV0 + cur * 8192;

        bf16x8 pf[4];   // PV A-frags, ksteps of 16 kv
#pragma unroll
        for (int sub = 0; sub < 2; sub++) {
            // QK^T (swapped): D[kv_local][q], kv subtile sub
            f32x16 accS = {};
            const u16* krow = sKc + (size_t)(sub * 32 + l31) * 128;
#pragma unroll
            for (int st = 0; st < 8; st++) {
                bf16x8 kf = *(const bf16x8*)(krow + (((st * 2 + hh) ^ lx) * 8));
                accS = __builtin_amdgcn_mfma_f32_32x32x16_bf16(kf, aq[st], accS, 0, 0, 0);
            }
            // static softmax: e = exp2(s*CEXP); direct fp32 e-sum (v9-validated),
            // pack pairs to bf16 (RNE) for PV
            u32 P[8];
#pragma unroll
            for (int g = 0; g < 4; g++) {
                float e0 = __builtin_amdgcn_exp2f(accS[4 * g + 0] * CEXP);
                float e1 = __builtin_amdgcn_exp2f(accS[4 * g + 1] * CEXP);
                float e2 = __builtin_amdgcn_exp2f(accS[4 * g + 2] * CEXP);
                float e3 = __builtin_amdgcn_exp2f(accS[4 * g + 3] * CEXP);
                lsum += (e0 + e1) + (e2 + e3);
                P[2 * g] = cvt_pk_bf16(e0, e1);
                P[2 * g + 1] = cvt_pk_bf16(e2, e3);
            }
            // permlane32_swap: exchange half-rows between lane l and l^32
            u32x2 a0 = __builtin_amdgcn_permlane32_swap(P[0], P[2], false, false);
            u32x2 a1 = __builtin_amdgcn_permlane32_swap(P[1], P[3], false, false);
            u32x2 a2 = __builtin_amdgcn_permlane32_swap(P[4], P[6], false, false);
            u32x2 a3 = __builtin_amdgcn_permlane32_swap(P[5], P[7], false, false);
            union { u32 u[4]; bf16x8 v; } f0, f1;
            f0.u[0] = a0.x; f0.u[1] = a1.x; f0.u[2] = a0.y; f0.u[3] = a1.y;
            f1.u[0] = a2.x; f1.u[1] = a3.x; f1.u[2] = a2.y; f1.u[3] = a3.y;
            pf[sub * 2] = f0.v;
            pf[sub * 2 + 1] = f1.v;
        }

        // PV: O[32 q][128 d] += P[32 x 64] * V[64 x 128]
#pragma unroll
        for (int db = 0; db < 4; db++) {
            const u16* vrow = sVc + (size_t)(db * 32 + l31) * 64;
#pragma unroll
            for (int ks = 0; ks < 4; ks++) {
                bf16x8 vf = *(const bf16x8*)(vrow + (((ks * 2 + hh) ^ lx) * 8));
                accO[db] = __builtin_amdgcn_mfma_f32_32x32x16_bf16(pf[ks], vf, accO[db], 0, 0, 0);
            }
        }

        __syncthreads();  // waits vmcnt(0): next tile's DMA (hidden under compute)
    }

    // ---- epilogue: combine half-sums, normalize, store ----
    lsum += __shfl_xor(lsum, 32, 64);    // lanes q and q+32 both hold denom(q=l31)
    float invq = 1.f / lsum;
    float inv[16];
#pragma unroll
    for (int r = 0; r < 16; r++) {
        int qloc = (r & 3) + 8 * (r >> 2) + 4 * hh;
        inv[r] = __shfl(invq, qloc, 64);
    }
#pragma unroll
    for (int db = 0; db < 4; db++) {
#pragma unroll
        for (int r = 0; r < 16; r++) {
            int qloc = (r & 3) + 8 * (r >> 2) + 4 * hh;
            outp[(size_t)(BS + q0w + qloc) * 2048 + hb * 128 + db * 32 + l31] =
                f2bf(accO[db][r] * inv[r]);
        }
    }
}

extern "C" void kernel_launch(void* const* d_in, const int* in_sizes, int n_in,
                              void* d_out, int out_size, void* d_ws, size_t ws_size,
                              hipStream_t stream) {
    const float* q  = (const float*)d_in[0];
    const float* k  = (const float*)d_in[1];
    const float* v  = (const float*)d_in[2];
    const float* Wq = (const float*)d_in[3];
    const float* bq = (const float*)d_in[4];
    const float* Wk = (const float*)d_in[5];
    const float* bk = (const float*)d_in[6];
    const float* Wv = (const float*)d_in[7];
    const float* bv = (const float*)d_in[8];
    const float* Wo = (const float*)d_in[9];
    const float* bo = (const float*)d_in[10];
    float* out = (float*)d_out;

    const int S = 2048, D = 2048, Dh = 128, M = 4096;  // M = B*S
    const int QKV = M * D;
    const int WDD = D * D;
    const int WDH = D * Dh;
    const int MDh = M * Dh;

    u16* ws   = (u16*)d_ws;
    u16* q_bf = ws;
    u16* k_bf = q_bf + QKV;
    u16* v_bf = k_bf + QKV;
    u16* WqT  = v_bf + QKV;
    u16* WoT  = WqT + WDD;
    u16* WkT  = WoT + WDD;
    u16* WvT  = WkT + WDH;
    u16* qhb  = WvT + WDH;       // [M][2048] bf16
    u16* khb  = qhb + QKV;       // [M][128]
    u16* vhTb = khb + MDh;       // [128][M]
    u16* aout = vhTb + MDh;      // [M][2048]
    float* kacc = (float*)(aout + QKV);  // [M][128] fp32
    float* vacc = kacc + MDh;            // [M][128] fp32

    // fused prep: cvt3 (24576) + Wq/Wo transpose (8192) + Wk/Wv transpose (512)
    //             + zero kacc/vacc (1024)  = 34304 blocks
    prep<<<dim3(34304), 256, 0, stream>>>(q, k, v, q_bf, k_bf, v_bf,
                                          Wq, WqT, Wo, WoT, Wk, WkT, Wv, WvT, kacc);

    gemm_bt3<u16><<<dim3(512), 256, 0, stream>>>(q_bf, WqT, bq, qhb, M, D, D, D);
    gemm_kv_sk<<<dim3(32, 2, 4), 256, 0, stream>>>(k_bf, v_bf, WkT, WvT, kacc, vacc, D, 512);
    cvt_kv<<<dim3(128, 4, 2), 256, 0, stream>>>(kacc, vacc, bk, bv, khb, vhTb, M);

    mqa_attn<<<dim3(16, 16, 2), 256, 0, stream>>>(qhb, khb, vhTb, aout, S);

    gemm_bt3<float><<<dim3(512), 256, 0, stream>>>(aout, WoT, bo, out, M, D, D, D);
}